// Round 15
// baseline (115.101 us; speedup 1.0000x reference)
//
#include <hip/hip_runtime.h>
#include <hip/hip_bf16.h>

#define N_NODES 4096
#define LOG2E 1.44269504088896340736f
#define JT 128                      // j-tile staged in LDS per block (dbuf)

typedef __attribute__((ext_vector_type(8))) short bf16x8;
typedef __attribute__((ext_vector_type(4))) short bf16x4;
typedef __attribute__((ext_vector_type(4))) float f32x4;
typedef __attribute__((ext_vector_type(16))) float f32x16;

static __device__ __forceinline__ ushort f2bf(float x) {
    union { float f; unsigned u; } v; v.f = x;
    unsigned u = v.u;
    return (ushort)((u + 0x7FFFu + ((u >> 16) & 1u)) >> 16);   // RNE
}
static __device__ __forceinline__ float bf2f(ushort h) {
    union { unsigned u; float f; } v; v.u = ((unsigned)h) << 16; return v.f;
}

// ---------------- W prep (small, precedes the fused gemm+mask kernel) --------
__global__ __launch_bounds__(256) void k_prep_w(const float* __restrict__ W1,
        ushort* __restrict__ Wh1, ushort* __restrict__ Wl1,
        const float* __restrict__ W2, ushort* __restrict__ Wh2, ushort* __restrict__ Wl2) {
    int idx = blockIdx.x * 256 + threadIdx.x;    // 640 blocks = 163840 items
    const float* W; ushort *Wh, *Wl; int kshift;
    if (idx < 131072) { W = W1; Wh = Wh1; Wl = Wl1; kshift = 8; }
    else { W = W2; Wh = Wh2; Wl = Wl2; idx -= 131072; kshift = 9; }
    int K = 1 << kshift;
    int n = idx & 63;
    int k = (idx >> 6) & (K - 1);
    int h = idx >> (6 + kshift);
    float v = W[idx + (kshift == 9 ? 0 : 0) * 0 + 0];   // base already selected
    // NOTE: idx was rebased for W2 above; W indexing uses the rebased idx
    v = W[idx];
    ushort hi = f2bf(v);
    union { unsigned u; float f; } hv; hv.u = ((unsigned)hi) << 16;
    ushort lo = f2bf(v - hv.f);
    size_t dst = ((size_t)h * 64 + n) * K + k;
    Wh[dst] = hi; Wl[dst] = lo;
}

// ---------------- FUSED layer-1 GEMM + mask-pack -----------------------------
// 3072 blocks x 512 thr, 2:1 interleaved roles: b%3<2 -> gemm (2048 blocks,
// MFMA/VALU-bound), b%3==2 -> mask-pack (1024 blocks, pure HBM stream of the
// 64MB adj). Complementary pipes overlap -> the ~10.5us mask HBM floor hides
// under gemm compute. gemm needs Wh/Wl (k_prep_w before); attn needs both
// outputs (after). 8-way K-split gemm identical to R14.
__global__ __launch_bounds__(512) void k_gemm_mask(const float* __restrict__ X,
        const ushort* __restrict__ Wh, const ushort* __restrict__ Wl,
        const float* __restrict__ a,
        const float* __restrict__ adj, unsigned* __restrict__ maskw,
        ushort* __restrict__ Ht, float* __restrict__ Rc,
        float* __restrict__ Tc, ushort* __restrict__ G2b) {
    const int K = 256;
    int b = blockIdx.x;
    int q = b / 3, r3 = b - q * 3;
    if (r3 == 2) {
        // ---- mask pack: 512 thr/block, 1024 blocks cover 4096*128 words ----
        int idx = q * 512 + threadIdx.x;
        int row = idx >> 7, w = idx & 127;
        const float4* ap = (const float4*)(adj + (size_t)row * N_NODES + w * 32);
        unsigned bits = 0;
#pragma unroll
        for (int qq = 0; qq < 8; ++qq) {
            float4 v = ap[qq];
            bits |= (v.x > 0.f ? 1u : 0u) << (qq * 4 + 0);
            bits |= (v.y > 0.f ? 1u : 0u) << (qq * 4 + 1);
            bits |= (v.z > 0.f ? 1u : 0u) << (qq * 4 + 2);
            bits |= (v.w > 0.f ? 1u : 0u) << (qq * 4 + 3);
        }
        maskw[idx] = bits;
        return;
    }
    int gb = q * 2 + r3;                         // 0..2047
    int head = gb >> 8;
    int i0 = (gb & 255) * 16;
    int t = threadIdx.x, wave = t >> 6, lane = t & 63;
    int c = lane & 15, g = lane >> 4;
    int kbeg = wave * 32;
    const float* xrow = X + (size_t)(i0 + c) * K;
    f32x4 acc[4] = {};
    {
        int k0 = kbeg;
        const float4* xp = (const float4*)(xrow + k0 + g * 8);
        float4 xa = xp[0], xb = xp[1];
        float xs[8] = {xa.x, xa.y, xa.z, xa.w, xb.x, xb.y, xb.z, xb.w};
        union { ushort s[8]; bf16x8 v; } ah, al;
#pragma unroll
        for (int e = 0; e < 8; ++e) {
            ushort hb = f2bf(xs[e]);
            ah.s[e] = hb;
            union { unsigned u; float f; } hv; hv.u = ((unsigned)hb) << 16;
            al.s[e] = f2bf(xs[e] - hv.f);
        }
#pragma unroll
        for (int nt = 0; nt < 4; ++nt) {
            size_t boff = ((size_t)head * 64 + nt * 16 + c) * K + k0 + g * 8;
            bf16x8 bh = *(const bf16x8*)(Wh + boff);
            bf16x8 bl = *(const bf16x8*)(Wl + boff);
            acc[nt] = __builtin_amdgcn_mfma_f32_16x16x32_bf16(ah.v, bh, acc[nt], 0, 0, 0);
            acc[nt] = __builtin_amdgcn_mfma_f32_16x16x32_bf16(al.v, bh, acc[nt], 0, 0, 0);
            acc[nt] = __builtin_amdgcn_mfma_f32_16x16x32_bf16(ah.v, bl, acc[nt], 0, 0, 0);
        }
    }
    __shared__ float red[8][64][17];
#pragma unroll
    for (int nt = 0; nt < 4; ++nt)
#pragma unroll
        for (int r = 0; r < 4; ++r)
            red[wave][lane][nt * 4 + r] = acc[nt][r];
    __syncthreads();
    if (wave != 0) return;
#pragma unroll
    for (int nt = 0; nt < 4; ++nt)
#pragma unroll
        for (int r = 0; r < 4; ++r) {
            float s = 0.f;
#pragma unroll
            for (int w = 0; w < 8; ++w) s += red[w][lane][nt * 4 + r];
            acc[nt][r] = s;
        }
    float a1v[4], a2v[4];
#pragma unroll
    for (int nt = 0; nt < 4; ++nt) {
        a1v[nt] = a[head * 128 + nt * 16 + c];
        a2v[nt] = a[head * 128 + 64 + nt * 16 + c];
    }
    float G2f[4];
#pragma unroll
    for (int r = 0; r < 4; ++r) {
        float f1 = 0.f, f2 = 0.f;
#pragma unroll
        for (int nt = 0; nt < 4; ++nt) {
            f1 = __builtin_fmaf(acc[nt][r], a1v[nt], f1);
            f2 = __builtin_fmaf(acc[nt][r], a2v[nt], f2);
        }
#pragma unroll
        for (int o = 1; o < 16; o <<= 1) {
            f1 += __shfl_xor(f1, o);
            f2 += __shfl_xor(f2, o);
        }
        float g2 = __builtin_amdgcn_exp2f(0.2f * LOG2E * f2);
        G2f[r] = g2;
        if (c == 0) {
            int i = i0 + g * 4 + r;
            Rc [head * N_NODES + i] = __builtin_amdgcn_exp2f(-0.8f * LOG2E * f1);
            Tc [head * N_NODES + i] = __builtin_amdgcn_exp2f( 0.8f * LOG2E * f2);
            G2b[head * N_NODES + i] = f2bf(g2);
        }
    }
#pragma unroll
    for (int nt = 0; nt < 4; ++nt) {
        union { ushort s[4]; bf16x4 v; } pk;
#pragma unroll
        for (int r = 0; r < 4; ++r) pk.s[r] = f2bf(acc[nt][r] * G2f[r]);
        *(bf16x4*)(Ht + ((size_t)head * 64 + nt * 16 + c) * N_NODES + i0 + g * 4) = pk.v;
    }
}

// ---------------- layer-2 GEMM with fused combine1 (accP bf16, JS1 unrolled) -
template<int JS1>
__global__ __launch_bounds__(512) void k_gemm2(const ushort* __restrict__ accP,
        const float* __restrict__ Zp,
        const ushort* __restrict__ Wh, const ushort* __restrict__ Wl,
        const float* __restrict__ a,
        ushort* __restrict__ Ht, float* __restrict__ Rc,
        float* __restrict__ Tc, ushort* __restrict__ G2b) {
    const int K = 512;
    int t = threadIdx.x, wave = t >> 6, lane = t & 63;
    int c = lane & 15, g = lane >> 4;
    int i0 = blockIdx.x * 16;
    int row = i0 + c;
    int hx = wave;
    float z = 0.f;
#pragma unroll
    for (int js = 0; js < JS1; ++js)
        z += Zp[(size_t)(hx * JS1 + js) * N_NODES + row];
    float rz = 1.0f / z;
    f32x4 acc[4] = {};
#pragma unroll
    for (int ki = 0; ki < 2; ++ki) {
        int k0 = wave * 64 + ki * 32;
        int n0 = ki * 32 + g * 8;
        float s[8] = {};
#pragma unroll
        for (int js = 0; js < JS1; ++js) {
            const ushort* apn = accP + ((size_t)(hx * JS1 + js) * N_NODES + row) * 64 + n0;
            union { int4 v; ushort u[8]; } uu;
            uu.v = *(const int4*)apn;
#pragma unroll
            for (int e = 0; e < 8; ++e) s[e] += bf2f(uu.u[e]);
        }
        union { ushort sh[8]; bf16x8 v; } ah, al;
#pragma unroll
        for (int e = 0; e < 8; ++e) {
            float v = s[e] * rz;
            v = v > 0.f ? v : (__builtin_amdgcn_exp2f(v * LOG2E) - 1.f);   // elu
            ushort hb = f2bf(v);
            ah.sh[e] = hb;
            union { unsigned u; float f; } hv; hv.u = ((unsigned)hb) << 16;
            al.sh[e] = f2bf(v - hv.f);
        }
#pragma unroll
        for (int nt = 0; nt < 4; ++nt) {
            size_t boff = ((size_t)(nt * 16 + c)) * K + k0 + g * 8;
            bf16x8 bh = *(const bf16x8*)(Wh + boff);
            bf16x8 bl = *(const bf16x8*)(Wl + boff);
            acc[nt] = __builtin_amdgcn_mfma_f32_16x16x32_bf16(ah.v, bh, acc[nt], 0, 0, 0);
            acc[nt] = __builtin_amdgcn_mfma_f32_16x16x32_bf16(al.v, bh, acc[nt], 0, 0, 0);
            acc[nt] = __builtin_amdgcn_mfma_f32_16x16x32_bf16(ah.v, bl, acc[nt], 0, 0, 0);
        }
    }
    __shared__ float red[8][64][17];
#pragma unroll
    for (int nt = 0; nt < 4; ++nt)
#pragma unroll
        for (int r = 0; r < 4; ++r)
            red[wave][lane][nt * 4 + r] = acc[nt][r];
    __syncthreads();
    if (wave != 0) return;
#pragma unroll
    for (int nt = 0; nt < 4; ++nt)
#pragma unroll
        for (int r = 0; r < 4; ++r) {
            float s = 0.f;
#pragma unroll
            for (int w = 0; w < 8; ++w) s += red[w][lane][nt * 4 + r];
            acc[nt][r] = s;
        }
    float a1v[4], a2v[4];
#pragma unroll
    for (int nt = 0; nt < 4; ++nt) {
        a1v[nt] = a[nt * 16 + c];
        a2v[nt] = a[64 + nt * 16 + c];
    }
    float G2f[4];
#pragma unroll
    for (int r = 0; r < 4; ++r) {
        float f1 = 0.f, f2 = 0.f;
#pragma unroll
        for (int nt = 0; nt < 4; ++nt) {
            f1 = __builtin_fmaf(acc[nt][r], a1v[nt], f1);
            f2 = __builtin_fmaf(acc[nt][r], a2v[nt], f2);
        }
#pragma unroll
        for (int o = 1; o < 16; o <<= 1) {
            f1 += __shfl_xor(f1, o);
            f2 += __shfl_xor(f2, o);
        }
        float g2 = __builtin_amdgcn_exp2f(0.2f * LOG2E * f2);
        G2f[r] = g2;
        if (c == 0) {
            int i = i0 + g * 4 + r;
            Rc [i] = __builtin_amdgcn_exp2f(-0.8f * LOG2E * f1);
            Tc [i] = __builtin_amdgcn_exp2f( 0.8f * LOG2E * f2);
            G2b[i] = f2bf(g2);
        }
    }
#pragma unroll
    for (int nt = 0; nt < 4; ++nt) {
        union { ushort s[4]; bf16x4 v; } pk;
#pragma unroll
        for (int r = 0; r < 4; ++r) pk.s[r] = f2bf(acc[nt][r] * G2f[r]);
        *(bf16x4*)(Ht + ((size_t)(nt * 16 + c)) * N_NODES + i0 + g * 4) = pk.v;
    }
}

// ---------------- masked flash attention (R12 order + setprio) ---------------
// R15: block order reverted to rb-FASTEST (R14's rb-major chunking raised
// FETCH 18.3->24.7 MB: consecutive blocks stopped sharing the Ht panel).
// s_setprio(1) wraps the MFMA cluster (T5: +4-7% on phase-split attn, m191).
template<int JS, int NH>
__global__ __launch_bounds__(256)
__attribute__((amdgpu_waves_per_eu(4, 4)))
void k_attn(const ushort* __restrict__ Ht,
        const float* __restrict__ Rc, const float* __restrict__ Tc,
        const ushort* __restrict__ G2b, const unsigned* __restrict__ maskw,
        ushort* __restrict__ accP, float* __restrict__ Zp) {
    int bid = blockIdx.x;
    int rb = bid & 31;                           // fastest: R12 locality
    int rem = bid >> 5;
    int js = rem % JS;
    int head = rem / JS;

    int t = threadIdx.x, wave = t >> 6, lane = t & 63;
    int r32 = lane & 31, half = lane >> 5;
    int i0b = rb * 128;
    int i0w = i0b + wave * 32;
    int irow = i0w + r32;
    const int jcount = N_NODES / JS;
    int j0 = js * jcount;
    const int ntiles = jcount / JT;
    const int ntm1 = ntiles - 1;
    int rot = (rb + js * 3 + head * 5) & ntm1;
    const float R = Rc[head * N_NODES + irow];

    __shared__ ushort Hs[2][64 * JT];           // 2 x 16 KB, swizzled chunks
    __shared__ unsigned Ms[2][512];             // 2 x 2 KB: [128 rows][4 words]
    __shared__ float Ts[2][JT];                 // 2 x 512 B
    __shared__ ushort G2s[2][JT];               // 2 x 256 B

    int nH = (wave * 4) * 4 + (lane >> 4);      // row for s=0; +4 per s
    const ushort* gspH[4];
#pragma unroll
    for (int s = 0; s < 4; ++s) {
        int n = nH + s * 4;
        gspH[s] = Ht + ((size_t)head * 64 + n) * N_NODES + j0
                + (((lane & 15) ^ (n & 7)) << 3);
    }
    const unsigned* msA = maskw + (size_t)(i0b + (2 * wave) * 16 + (lane >> 2)) * 128
                        + (j0 >> 5) + (lane & 3);
    const unsigned* msB = msA + (size_t)16 * 128;
    const float*  tsrcA = Tc  + (size_t)head * N_NODES + j0 + lane;        // wave 1
    const float*  tsrcB = Tc  + (size_t)head * N_NODES + j0 + 64 + lane;   // wave 2
    const ushort* gsrc  = G2b + (size_t)head * N_NODES + j0 + lane * 2;    // wave 3

    auto stage = [&](int b, int tile) {
        int go = tile * JT;
#pragma unroll
        for (int s = 0; s < 4; ++s)
            __builtin_amdgcn_global_load_lds((const unsigned*)(gspH[s] + go),
                    (unsigned*)&Hs[b][(wave * 4 + s) * 512], 16, 0, 0);
        __builtin_amdgcn_global_load_lds(msA + tile * 4,
                (unsigned*)&Ms[b][(2 * wave) * 64], 4, 0, 0);
        __builtin_amdgcn_global_load_lds(msB + tile * 4,
                (unsigned*)&Ms[b][(2 * wave + 1) * 64], 4, 0, 0);
        if (wave == 1)
            __builtin_amdgcn_global_load_lds((const unsigned*)(tsrcA + go),
                    (unsigned*)&Ts[b][0], 4, 0, 0);
        else if (wave == 2)
            __builtin_amdgcn_global_load_lds((const unsigned*)(tsrcB + go),
                    (unsigned*)&Ts[b][64], 4, 0, 0);
        else if (wave == 3)
            __builtin_amdgcn_global_load_lds((const unsigned*)(gsrc + go),
                    (unsigned*)&G2s[b][0], 4, 0, 0);
    };

    f32x16 acc0 = {}, acc1 = {}, acc2 = {};

    stage(0, rot);
    int buf = 0;
    for (int tt = 0; tt < ntiles; ++tt) {
        if (tt + 1 < ntiles) {
            stage(buf ^ 1, (tt + 1 + rot) & ntm1);
            if (wave == 0) asm volatile("s_waitcnt vmcnt(6)");
            else           asm volatile("s_waitcnt vmcnt(7)");
        } else {
            asm volatile("s_waitcnt vmcnt(0)");
        }
        __builtin_amdgcn_s_barrier();

        const char* hb = (const char*)&Hs[buf][0];
        union { uint4 v; unsigned w[4]; } mw;
        mw.v = *(const uint4*)&Ms[buf][(wave * 32 + r32) * 4];
#pragma unroll
        for (int itr = 0; itr < JT / 16; ++itr) {
            unsigned phys = (unsigned)(((itr * 2 + half) ^ (r32 & 7)) << 4);
            bf16x8 b0 = *(const bf16x8*)(hb + r32 * 256 + phys);
            bf16x8 b1 = *(const bf16x8*)(hb + (32 + r32) * 256 + phys);
            bf16x8 bg = *(const bf16x8*)(&G2s[buf][itr * 16 + half * 8]);
            unsigned mword = mw.w[itr >> 1];
            unsigned mshift = mword >> ((itr & 1) * 16 + half * 8);
            const float* tp = &Ts[buf][itr * 16 + half * 8];
            float4 ta = *(const float4*)tp;
            float4 tb = *(const float4*)(tp + 4);
            float tv[8] = {ta.x, ta.y, ta.z, ta.w, tb.x, tb.y, tb.z, tb.w};
            float p[8];
#pragma unroll
            for (int e = 0; e < 8; ++e) {
                int sm = (int)(mshift << (31 - e)) >> 31;        // bfe_i32 pattern
                float pe = fmaxf(tv[e], R);
                union { float f; int i; } pv; pv.f = pe;
                pv.i &= sm;
                p[e] = pv.f;
            }
            union { unsigned w[4]; bf16x8 v; } pa;
#pragma unroll
            for (int q = 0; q < 4; ++q)
                asm("v_cvt_pk_bf16_f32 %0, %1, %2"
                    : "=v"(pa.w[q]) : "v"(p[2 * q]), "v"(p[2 * q + 1]));
            __builtin_amdgcn_s_setprio(1);
            acc0 = __builtin_amdgcn_mfma_f32_32x32x16_bf16(pa.v, b0, acc0, 0, 0, 0);
            acc1 = __builtin_amdgcn_mfma_f32_32x32x16_bf16(pa.v, b1, acc1, 0, 0, 0);
            acc2 = __builtin_amdgcn_mfma_f32_32x32x16_bf16(pa.v, bg, acc2, 0, 0, 0);
            __builtin_amdgcn_s_setprio(0);
        }
        __builtin_amdgcn_s_barrier();
        buf ^= 1;
    }
    int slice = head * JS + js;
    if (r32 == 0) {
#pragma unroll
        for (int reg = 0; reg < 16; ++reg) {
            int drow = (reg & 3) + 8 * (reg >> 2) + 4 * half;
            Zp[(size_t)slice * N_NODES + i0w + drow] = acc2[reg];
        }
    }
    ushort* ap = accP + ((size_t)slice * N_NODES + i0w) * 64;
#pragma unroll
    for (int reg = 0; reg < 16; ++reg) {
        int drow = (reg & 3) + 8 * (reg >> 2) + 4 * half;
        ap[drow * 64 + r32] = f2bf(acc0[reg]);
        ap[drow * 64 + 32 + r32] = f2bf(acc1[reg]);
    }
}

// ---------------- combine partials (layer 2 / final output, JS unrolled) -----
template<int JS>
__global__ __launch_bounds__(256) void k_combine2(const ushort* __restrict__ accP,
        const float* __restrict__ Zp, float* __restrict__ out) {
    int idx = blockIdx.x * 256 + threadIdx.x;    // 4096*64
    int n = idx & 63, i = idx >> 6;
    float s = 0.f, z = 0.f;
#pragma unroll
    for (int j = 0; j < JS; ++j) {
        s += bf2f(accP[((size_t)j * N_NODES + i) * 64 + n]);
        z += Zp[(size_t)j * N_NODES + i];
    }
    out[idx] = s / z;
}

extern "C" void kernel_launch(void* const* d_in, const int* in_sizes, int n_in,
                              void* d_out, int out_size, void* d_ws, size_t ws_size,
                              hipStream_t stream) {
    const float* features = (const float*)d_in[0];
    const float* adj      = (const float*)d_in[1];
    const float* W_heads  = (const float*)d_in[2];
    const float* a_heads  = (const float*)d_in[3];
    const float* W_out    = (const float*)d_in[4];
    const float* a_out    = (const float*)d_in[5];
    float* out = (float*)d_out;

    // fixed ~7.6 MB; per-slice bf16 accP + f32 Zp ~0.55 MB
    int tier;
    if (ws_size >= 26000000)      tier = 2;      // JS1=4, JS2=32
    else if (ws_size >= 17500000) tier = 1;      // JS1=2, JS2=16
    else                          tier = 0;      // JS1=1, JS2=8
    int JS1 = tier == 2 ? 4 : (tier == 1 ? 2 : 1);
    int JS2 = tier == 2 ? 32 : (tier == 1 ? 16 : 8);
    int slices = (8 * JS1 > JS2) ? 8 * JS1 : JS2;

    char* ws = (char*)d_ws;
    size_t off = 0;
    auto alloc = [&](size_t bytes) -> void* {
        void* p = ws + off; off = (off + bytes + 255) & ~(size_t)255; return p;
    };
    unsigned* maskw = (unsigned*)alloc((size_t)N_NODES * 128 * 4);
    ushort* Ht1 = (ushort*)alloc((size_t)8 * 64 * N_NODES * 2);   // n-major
    ushort* Ht2 = (ushort*)alloc((size_t)64 * N_NODES * 2);
    float* Rc1  = (float*)alloc((size_t)8 * N_NODES * 4);
    float* Tc1  = (float*)alloc((size_t)8 * N_NODES * 4);
    ushort* G2b1 = (ushort*)alloc((size_t)8 * N_NODES * 2);
    float* Rc2  = (float*)alloc((size_t)N_NODES * 4);
    float* Tc2  = (float*)alloc((size_t)N_NODES * 4);
    ushort* G2b2 = (ushort*)alloc((size_t)N_NODES * 2);
    ushort* Wh1 = (ushort*)alloc((size_t)8 * 64 * 256 * 2);
    ushort* Wl1 = (ushort*)alloc((size_t)8 * 64 * 256 * 2);
    ushort* Wh2 = (ushort*)alloc((size_t)64 * 512 * 2);
    ushort* Wl2 = (ushort*)alloc((size_t)64 * 512 * 2);
    ushort* accP = (ushort*)alloc((size_t)slices * N_NODES * 64 * 2);
    float* Zp   = (float*)alloc((size_t)slices * N_NODES * 4);

    hipLaunchKernelGGL(k_prep_w, dim3(640), dim3(256), 0, stream,
                       W_heads, Wh1, Wl1, W_out, Wh2, Wl2);
    // layer 1: gemm fused with mask-pack (HBM stream overlaps MFMA compute)
    hipLaunchKernelGGL(k_gemm_mask, dim3(3072), dim3(512), 0, stream,
                       features, Wh1, Wl1, a_heads, adj, maskw,
                       Ht1, Rc1, Tc1, G2b1);
    if (tier == 2)
        hipLaunchKernelGGL((k_attn<4, 8>), dim3(32 * 4 * 8), dim3(256), 0, stream,
                           Ht1, Rc1, Tc1, G2b1, maskw, accP, Zp);
    else if (tier == 1)
        hipLaunchKernelGGL((k_attn<2, 8>), dim3(32 * 2 * 8), dim3(256), 0, stream,
                           Ht1, Rc1, Tc1, G2b1, maskw, accP, Zp);
    else
        hipLaunchKernelGGL((k_attn<1, 8>), dim3(32 * 1 * 8), dim3(256), 0, stream,
                           Ht1, Rc1, Tc1, G2b1, maskw, accP, Zp);
    // layer 2 (combine1 fused into the GEMM)
    if (tier == 2)
        hipLaunchKernelGGL((k_gemm2<4>), dim3(N_NODES / 16), dim3(512), 0, stream,
                           accP, Zp, Wh2, Wl2, a_out, Ht2, Rc2, Tc2, G2b2);
    else if (tier == 1)
        hipLaunchKernelGGL((k_gemm2<2>), dim3(N_NODES / 16), dim3(512), 0, stream,
                           accP, Zp, Wh2, Wl2, a_out, Ht2, Rc2, Tc2, G2b2);
    else
        hipLaunchKernelGGL((k_gemm2<1>), dim3(N_NODES / 16), dim3(512), 0, stream,
                           accP, Zp, Wh2, Wl2, a_out, Ht2, Rc2, Tc2, G2b2);
    if (tier == 2) {
        hipLaunchKernelGGL((k_attn<32, 1>), dim3(32 * 32), dim3(256), 0, stream,
                           Ht2, Rc2, Tc2, G2b2, maskw, accP, Zp);
        hipLaunchKernelGGL((k_combine2<32>), dim3(N_NODES * 64 / 256), dim3(256), 0, stream,
                           accP, Zp, out);
    } else if (tier == 1) {
        hipLaunchKernelGGL((k_attn<16, 1>), dim3(32 * 16), dim3(256), 0, stream,
                           Ht2, Rc2, Tc2, G2b2, maskw, accP, Zp);
        hipLaunchKernelGGL((k_combine2<16>), dim3(N_NODES * 64 / 256), dim3(256), 0, stream,
                           accP, Zp, out);
    } else {
        hipLaunchKernelGGL((k_attn<8, 1>), dim3(32 * 8), dim3(256), 0, stream,
                           Ht2, Rc2, Tc2, G2b2, maskw, accP, Zp);
        hipLaunchKernelGGL((k_combine2<8>), dim3(N_NODES * 64 / 256), dim3(256), 0, stream,
                           accP, Zp, out);
    }
}

// Round 16
// 112.148 us; speedup vs baseline: 1.0263x; 1.0263x over previous
//
#include <hip/hip_runtime.h>
#include <hip/hip_bf16.h>

#define N_NODES 4096
#define LOG2E 1.44269504088896340736f
#define JT 128                      // j-tile staged in LDS per block (dbuf)

typedef __attribute__((ext_vector_type(8))) short bf16x8;
typedef __attribute__((ext_vector_type(4))) short bf16x4;
typedef __attribute__((ext_vector_type(4))) float f32x4;
typedef __attribute__((ext_vector_type(16))) float f32x16;

static __device__ __forceinline__ ushort f2bf(float x) {
    union { float f; unsigned u; } v; v.f = x;
    unsigned u = v.u;
    return (ushort)((u + 0x7FFFu + ((u >> 16) & 1u)) >> 16);   // RNE
}
static __device__ __forceinline__ float bf2f(ushort h) {
    union { unsigned u; float f; } v; v.u = ((unsigned)h) << 16; return v.f;
}

// ---------------- fused prologue: pack_mask + prep_w(heads) + prep_w(out) ----
__global__ __launch_bounds__(256) void k_prologue(const float* __restrict__ adj,
        unsigned* __restrict__ maskw,
        const float* __restrict__ W1, ushort* __restrict__ Wh1, ushort* __restrict__ Wl1,
        const float* __restrict__ W2, ushort* __restrict__ Wh2, ushort* __restrict__ Wl2) {
    int b = blockIdx.x, t = threadIdx.x;
    if (b < 2048) {
        int idx = b * 256 + t;                       // 4096*128 words
        int row = idx >> 7, w = idx & 127;
        const float4* ap = (const float4*)(adj + (size_t)row * N_NODES + w * 32);
        unsigned bits = 0;
#pragma unroll
        for (int q = 0; q < 8; ++q) {
            float4 v = ap[q];
            bits |= (v.x > 0.f ? 1u : 0u) << (q * 4 + 0);
            bits |= (v.y > 0.f ? 1u : 0u) << (q * 4 + 1);
            bits |= (v.z > 0.f ? 1u : 0u) << (q * 4 + 2);
            bits |= (v.w > 0.f ? 1u : 0u) << (q * 4 + 3);
        }
        maskw[idx] = bits;
    } else {
        const float* W; ushort *Wh, *Wl; int idx, kshift;
        if (b < 2560) { W = W1; Wh = Wh1; Wl = Wl1; idx = (b - 2048) * 256 + t; kshift = 8; }
        else          { W = W2; Wh = Wh2; Wl = Wl2; idx = (b - 2560) * 256 + t; kshift = 9; }
        int K = 1 << kshift;
        int n = idx & 63;
        int k = (idx >> 6) & (K - 1);
        int h = idx >> (6 + kshift);
        float v = W[idx];
        ushort hi = f2bf(v);
        union { unsigned u; float f; } hv; hv.u = ((unsigned)hi) << 16;
        ushort lo = f2bf(v - hv.f);
        size_t dst = ((size_t)h * 64 + n) * K + k;
        Wh[dst] = hi; Wl[dst] = lo;
    }
}

// ---------------- layer-1 H = X @ W (3-term split bf16 MFMA), 8-way K-split --
__global__ __launch_bounds__(512) void k_gemm_h(const float* __restrict__ X,
        const ushort* __restrict__ Wh, const ushort* __restrict__ Wl,
        const float* __restrict__ a,
        ushort* __restrict__ Ht, float* __restrict__ Rc,
        float* __restrict__ Tc, ushort* __restrict__ G2b, int K) {
    int head = blockIdx.y;
    int t = threadIdx.x, wave = t >> 6, lane = t & 63;
    int c = lane & 15, g = lane >> 4;
    int i0 = blockIdx.x * 16;
    int kq = K >> 3;
    int kbeg = wave * kq;
    const float* xrow = X + (size_t)(i0 + c) * K;
    f32x4 acc[4] = {};
    for (int k0 = kbeg; k0 < kbeg + kq; k0 += 32) {
        const float4* xp = (const float4*)(xrow + k0 + g * 8);
        float4 xa = xp[0], xb = xp[1];
        float xs[8] = {xa.x, xa.y, xa.z, xa.w, xb.x, xb.y, xb.z, xb.w};
        union { ushort s[8]; bf16x8 v; } ah, al;
#pragma unroll
        for (int e = 0; e < 8; ++e) {
            ushort hb = f2bf(xs[e]);
            ah.s[e] = hb;
            union { unsigned u; float f; } hv; hv.u = ((unsigned)hb) << 16;
            al.s[e] = f2bf(xs[e] - hv.f);
        }
#pragma unroll
        for (int nt = 0; nt < 4; ++nt) {
            size_t boff = ((size_t)head * 64 + nt * 16 + c) * K + k0 + g * 8;
            bf16x8 bh = *(const bf16x8*)(Wh + boff);
            bf16x8 bl = *(const bf16x8*)(Wl + boff);
            acc[nt] = __builtin_amdgcn_mfma_f32_16x16x32_bf16(ah.v, bh, acc[nt], 0, 0, 0);
            acc[nt] = __builtin_amdgcn_mfma_f32_16x16x32_bf16(al.v, bh, acc[nt], 0, 0, 0);
            acc[nt] = __builtin_amdgcn_mfma_f32_16x16x32_bf16(ah.v, bl, acc[nt], 0, 0, 0);
        }
    }
    __shared__ float red[8][64][17];
#pragma unroll
    for (int nt = 0; nt < 4; ++nt)
#pragma unroll
        for (int r = 0; r < 4; ++r)
            red[wave][lane][nt * 4 + r] = acc[nt][r];
    __syncthreads();
    if (wave != 0) return;
#pragma unroll
    for (int nt = 0; nt < 4; ++nt)
#pragma unroll
        for (int r = 0; r < 4; ++r) {
            float s = 0.f;
#pragma unroll
            for (int w = 0; w < 8; ++w) s += red[w][lane][nt * 4 + r];
            acc[nt][r] = s;
        }
    float a1v[4], a2v[4];
#pragma unroll
    for (int nt = 0; nt < 4; ++nt) {
        a1v[nt] = a[head * 128 + nt * 16 + c];
        a2v[nt] = a[head * 128 + 64 + nt * 16 + c];
    }
    float G2f[4];
#pragma unroll
    for (int r = 0; r < 4; ++r) {
        float f1 = 0.f, f2 = 0.f;
#pragma unroll
        for (int nt = 0; nt < 4; ++nt) {
            f1 = __builtin_fmaf(acc[nt][r], a1v[nt], f1);
            f2 = __builtin_fmaf(acc[nt][r], a2v[nt], f2);
        }
#pragma unroll
        for (int o = 1; o < 16; o <<= 1) {
            f1 += __shfl_xor(f1, o);
            f2 += __shfl_xor(f2, o);
        }
        float g2 = __builtin_amdgcn_exp2f(0.2f * LOG2E * f2);
        G2f[r] = g2;
        if (c == 0) {
            int i = i0 + g * 4 + r;
            Rc [head * N_NODES + i] = __builtin_amdgcn_exp2f(-0.8f * LOG2E * f1);
            Tc [head * N_NODES + i] = __builtin_amdgcn_exp2f( 0.8f * LOG2E * f2);
            G2b[head * N_NODES + i] = f2bf(g2);
        }
    }
#pragma unroll
    for (int nt = 0; nt < 4; ++nt) {
        union { ushort s[4]; bf16x4 v; } pk;
#pragma unroll
        for (int r = 0; r < 4; ++r) pk.s[r] = f2bf(acc[nt][r] * G2f[r]);
        *(bf16x4*)(Ht + ((size_t)head * 64 + nt * 16 + c) * N_NODES + i0 + g * 4) = pk.v;
    }
}

// ---------------- layer-2 GEMM with fused combine1 (accP bf16, JS1 unrolled) -
template<int JS1>
__global__ __launch_bounds__(512) void k_gemm2(const ushort* __restrict__ accP,
        const float* __restrict__ Zp,
        const ushort* __restrict__ Wh, const ushort* __restrict__ Wl,
        const float* __restrict__ a,
        ushort* __restrict__ Ht, float* __restrict__ Rc,
        float* __restrict__ Tc, ushort* __restrict__ G2b) {
    const int K = 512;
    int t = threadIdx.x, wave = t >> 6, lane = t & 63;
    int c = lane & 15, g = lane >> 4;
    int i0 = blockIdx.x * 16;
    int row = i0 + c;
    int hx = wave;
    float z = 0.f;
#pragma unroll
    for (int js = 0; js < JS1; ++js)
        z += Zp[(size_t)(hx * JS1 + js) * N_NODES + row];
    float rz = 1.0f / z;
    f32x4 acc[4] = {};
#pragma unroll
    for (int ki = 0; ki < 2; ++ki) {
        int k0 = wave * 64 + ki * 32;
        int n0 = ki * 32 + g * 8;
        float s[8] = {};
#pragma unroll
        for (int js = 0; js < JS1; ++js) {
            const ushort* apn = accP + ((size_t)(hx * JS1 + js) * N_NODES + row) * 64 + n0;
            union { int4 v; ushort u[8]; } uu;
            uu.v = *(const int4*)apn;
#pragma unroll
            for (int e = 0; e < 8; ++e) s[e] += bf2f(uu.u[e]);
        }
        union { ushort sh[8]; bf16x8 v; } ah, al;
#pragma unroll
        for (int e = 0; e < 8; ++e) {
            float v = s[e] * rz;
            v = v > 0.f ? v : (__builtin_amdgcn_exp2f(v * LOG2E) - 1.f);   // elu
            ushort hb = f2bf(v);
            ah.sh[e] = hb;
            union { unsigned u; float f; } hv; hv.u = ((unsigned)hb) << 16;
            al.sh[e] = f2bf(v - hv.f);
        }
#pragma unroll
        for (int nt = 0; nt < 4; ++nt) {
            size_t boff = ((size_t)(nt * 16 + c)) * K + k0 + g * 8;
            bf16x8 bh = *(const bf16x8*)(Wh + boff);
            bf16x8 bl = *(const bf16x8*)(Wl + boff);
            acc[nt] = __builtin_amdgcn_mfma_f32_16x16x32_bf16(ah.v, bh, acc[nt], 0, 0, 0);
            acc[nt] = __builtin_amdgcn_mfma_f32_16x16x32_bf16(al.v, bh, acc[nt], 0, 0, 0);
            acc[nt] = __builtin_amdgcn_mfma_f32_16x16x32_bf16(ah.v, bl, acc[nt], 0, 0, 0);
        }
    }
    __shared__ float red[8][64][17];
#pragma unroll
    for (int nt = 0; nt < 4; ++nt)
#pragma unroll
        for (int r = 0; r < 4; ++r)
            red[wave][lane][nt * 4 + r] = acc[nt][r];
    __syncthreads();
    if (wave != 0) return;
#pragma unroll
    for (int nt = 0; nt < 4; ++nt)
#pragma unroll
        for (int r = 0; r < 4; ++r) {
            float s = 0.f;
#pragma unroll
            for (int w = 0; w < 8; ++w) s += red[w][lane][nt * 4 + r];
            acc[nt][r] = s;
        }
    float a1v[4], a2v[4];
#pragma unroll
    for (int nt = 0; nt < 4; ++nt) {
        a1v[nt] = a[nt * 16 + c];
        a2v[nt] = a[64 + nt * 16 + c];
    }
    float G2f[4];
#pragma unroll
    for (int r = 0; r < 4; ++r) {
        float f1 = 0.f, f2 = 0.f;
#pragma unroll
        for (int nt = 0; nt < 4; ++nt) {
            f1 = __builtin_fmaf(acc[nt][r], a1v[nt], f1);
            f2 = __builtin_fmaf(acc[nt][r], a2v[nt], f2);
        }
#pragma unroll
        for (int o = 1; o < 16; o <<= 1) {
            f1 += __shfl_xor(f1, o);
            f2 += __shfl_xor(f2, o);
        }
        float g2 = __builtin_amdgcn_exp2f(0.2f * LOG2E * f2);
        G2f[r] = g2;
        if (c == 0) {
            int i = i0 + g * 4 + r;
            Rc [i] = __builtin_amdgcn_exp2f(-0.8f * LOG2E * f1);
            Tc [i] = __builtin_amdgcn_exp2f( 0.8f * LOG2E * f2);
            G2b[i] = f2bf(g2);
        }
    }
#pragma unroll
    for (int nt = 0; nt < 4; ++nt) {
        union { ushort s[4]; bf16x4 v; } pk;
#pragma unroll
        for (int r = 0; r < 4; ++r) pk.s[r] = f2bf(acc[nt][r] * G2f[r]);
        *(bf16x4*)(Ht + ((size_t)(nt * 16 + c)) * N_NODES + i0 + g * 4) = pk.v;
    }
}

// ---------------- masked flash attention (rb-fastest + bfe + setprio) --------
template<int JS, int NH>
__global__ __launch_bounds__(256)
__attribute__((amdgpu_waves_per_eu(4, 4)))
void k_attn(const ushort* __restrict__ Ht,
        const float* __restrict__ Rc, const float* __restrict__ Tc,
        const ushort* __restrict__ G2b, const unsigned* __restrict__ maskw,
        ushort* __restrict__ accP, float* __restrict__ Zp) {
    int bid = blockIdx.x;
    int rb = bid & 31;                           // fastest: Ht-panel locality
    int rem = bid >> 5;
    int js = rem % JS;
    int head = rem / JS;

    int t = threadIdx.x, wave = t >> 6, lane = t & 63;
    int r32 = lane & 31, half = lane >> 5;
    int i0b = rb * 128;
    int i0w = i0b + wave * 32;
    int irow = i0w + r32;
    const int jcount = N_NODES / JS;
    int j0 = js * jcount;
    const int ntiles = jcount / JT;
    const int ntm1 = ntiles - 1;
    int rot = (rb + js * 3 + head * 5) & ntm1;
    const float R = Rc[head * N_NODES + irow];

    __shared__ ushort Hs[2][64 * JT];           // 2 x 16 KB, swizzled chunks
    __shared__ unsigned Ms[2][512];             // 2 x 2 KB: [128 rows][4 words]
    __shared__ float Ts[2][JT];                 // 2 x 512 B
    __shared__ ushort G2s[2][JT];               // 2 x 256 B

    int nH = (wave * 4) * 4 + (lane >> 4);      // row for s=0; +4 per s
    const ushort* gspH[4];
#pragma unroll
    for (int s = 0; s < 4; ++s) {
        int n = nH + s * 4;
        gspH[s] = Ht + ((size_t)head * 64 + n) * N_NODES + j0
                + (((lane & 15) ^ (n & 7)) << 3);
    }
    const unsigned* msA = maskw + (size_t)(i0b + (2 * wave) * 16 + (lane >> 2)) * 128
                        + (j0 >> 5) + (lane & 3);
    const unsigned* msB = msA + (size_t)16 * 128;
    const float*  tsrcA = Tc  + (size_t)head * N_NODES + j0 + lane;        // wave 1
    const float*  tsrcB = Tc  + (size_t)head * N_NODES + j0 + 64 + lane;   // wave 2
    const ushort* gsrc  = G2b + (size_t)head * N_NODES + j0 + lane * 2;    // wave 3

    auto stage = [&](int b, int tile) {
        int go = tile * JT;
#pragma unroll
        for (int s = 0; s < 4; ++s)
            __builtin_amdgcn_global_load_lds((const unsigned*)(gspH[s] + go),
                    (unsigned*)&Hs[b][(wave * 4 + s) * 512], 16, 0, 0);
        __builtin_amdgcn_global_load_lds(msA + tile * 4,
                (unsigned*)&Ms[b][(2 * wave) * 64], 4, 0, 0);
        __builtin_amdgcn_global_load_lds(msB + tile * 4,
                (unsigned*)&Ms[b][(2 * wave + 1) * 64], 4, 0, 0);
        if (wave == 1)
            __builtin_amdgcn_global_load_lds((const unsigned*)(tsrcA + go),
                    (unsigned*)&Ts[b][0], 4, 0, 0);
        else if (wave == 2)
            __builtin_amdgcn_global_load_lds((const unsigned*)(tsrcB + go),
                    (unsigned*)&Ts[b][64], 4, 0, 0);
        else if (wave == 3)
            __builtin_amdgcn_global_load_lds((const unsigned*)(gsrc + go),
                    (unsigned*)&G2s[b][0], 4, 0, 0);
    };

    f32x16 acc0 = {}, acc1 = {}, acc2 = {};

    stage(0, rot);
    int buf = 0;
    for (int tt = 0; tt < ntiles; ++tt) {
        if (tt + 1 < ntiles) {
            stage(buf ^ 1, (tt + 1 + rot) & ntm1);
            if (wave == 0) asm volatile("s_waitcnt vmcnt(6)");
            else           asm volatile("s_waitcnt vmcnt(7)");
        } else {
            asm volatile("s_waitcnt vmcnt(0)");
        }
        __builtin_amdgcn_s_barrier();

        const char* hb = (const char*)&Hs[buf][0];
        union { uint4 v; unsigned w[4]; } mw;
        mw.v = *(const uint4*)&Ms[buf][(wave * 32 + r32) * 4];
#pragma unroll
        for (int itr = 0; itr < JT / 16; ++itr) {
            unsigned phys = (unsigned)(((itr * 2 + half) ^ (r32 & 7)) << 4);
            bf16x8 b0 = *(const bf16x8*)(hb + r32 * 256 + phys);
            bf16x8 b1 = *(const bf16x8*)(hb + (32 + r32) * 256 + phys);
            bf16x8 bg = *(const bf16x8*)(&G2s[buf][itr * 16 + half * 8]);
            unsigned mword = mw.w[itr >> 1];
            unsigned mshift = mword >> ((itr & 1) * 16 + half * 8);
            const float* tp = &Ts[buf][itr * 16 + half * 8];
            float4 ta = *(const float4*)tp;
            float4 tb = *(const float4*)(tp + 4);
            float tv[8] = {ta.x, ta.y, ta.z, ta.w, tb.x, tb.y, tb.z, tb.w};
            float p[8];
#pragma unroll
            for (int e = 0; e < 8; ++e) {
                int sm;
                asm("v_bfe_i32 %0, %1, %2, 1" : "=v"(sm) : "v"(mshift), "i"(e));
                float pe = fmaxf(tv[e], R);
                union { float f; int i; } pv; pv.f = pe;
                pv.i &= sm;
                p[e] = pv.f;
            }
            union { unsigned w[4]; bf16x8 v; } pa;
#pragma unroll
            for (int q = 0; q < 4; ++q)
                asm("v_cvt_pk_bf16_f32 %0, %1, %2"
                    : "=v"(pa.w[q]) : "v"(p[2 * q]), "v"(p[2 * q + 1]));
            __builtin_amdgcn_s_setprio(1);
            acc0 = __builtin_amdgcn_mfma_f32_32x32x16_bf16(pa.v, b0, acc0, 0, 0, 0);
            acc1 = __builtin_amdgcn_mfma_f32_32x32x16_bf16(pa.v, b1, acc1, 0, 0, 0);
            acc2 = __builtin_amdgcn_mfma_f32_32x32x16_bf16(pa.v, bg, acc2, 0, 0, 0);
            __builtin_amdgcn_s_setprio(0);
        }
        __builtin_amdgcn_s_barrier();
        buf ^= 1;
    }
    int slice = head * JS + js;
    if (r32 == 0) {
#pragma unroll
        for (int reg = 0; reg < 16; ++reg) {
            int drow = (reg & 3) + 8 * (reg >> 2) + 4 * half;
            Zp[(size_t)slice * N_NODES + i0w + drow] = acc2[reg];
        }
    }
    ushort* ap = accP + ((size_t)slice * N_NODES + i0w) * 64;
#pragma unroll
    for (int reg = 0; reg < 16; ++reg) {
        int drow = (reg & 3) + 8 * (reg >> 2) + 4 * half;
        ap[drow * 64 + r32] = f2bf(acc0[reg]);
        ap[drow * 64 + 32 + r32] = f2bf(acc1[reg]);
    }
}

// ---------------- combine partials (layer 2 / final output, JS unrolled) -----
template<int JS>
__global__ __launch_bounds__(256) void k_combine2(const ushort* __restrict__ accP,
        const float* __restrict__ Zp, float* __restrict__ out) {
    int idx = blockIdx.x * 256 + threadIdx.x;    // 4096*64
    int n = idx & 63, i = idx >> 6;
    float s = 0.f, z = 0.f;
#pragma unroll
    for (int j = 0; j < JS; ++j) {
        s += bf2f(accP[((size_t)j * N_NODES + i) * 64 + n]);
        z += Zp[(size_t)j * N_NODES + i];
    }
    out[idx] = s / z;
}

extern "C" void kernel_launch(void* const* d_in, const int* in_sizes, int n_in,
                              void* d_out, int out_size, void* d_ws, size_t ws_size,
                              hipStream_t stream) {
    const float* features = (const float*)d_in[0];
    const float* adj      = (const float*)d_in[1];
    const float* W_heads  = (const float*)d_in[2];
    const float* a_heads  = (const float*)d_in[3];
    const float* W_out    = (const float*)d_in[4];
    const float* a_out    = (const float*)d_in[5];
    float* out = (float*)d_out;

    int tier;
    if (ws_size >= 26000000)      tier = 2;      // JS1=4, JS2=32
    else if (ws_size >= 17500000) tier = 1;      // JS1=2, JS2=16
    else                          tier = 0;      // JS1=1, JS2=8
    int JS1 = tier == 2 ? 4 : (tier == 1 ? 2 : 1);
    int JS2 = tier == 2 ? 32 : (tier == 1 ? 16 : 8);
    int slices = (8 * JS1 > JS2) ? 8 * JS1 : JS2;

    char* ws = (char*)d_ws;
    size_t off = 0;
    auto alloc = [&](size_t bytes) -> void* {
        void* p = ws + off; off = (off + bytes + 255) & ~(size_t)255; return p;
    };
    unsigned* maskw = (unsigned*)alloc((size_t)N_NODES * 128 * 4);
    ushort* Ht1 = (ushort*)alloc((size_t)8 * 64 * N_NODES * 2);   // n-major
    ushort* Ht2 = (ushort*)alloc((size_t)64 * N_NODES * 2);
    float* Rc1  = (float*)alloc((size_t)8 * N_NODES * 4);
    float* Tc1  = (float*)alloc((size_t)8 * N_NODES * 4);
    ushort* G2b1 = (ushort*)alloc((size_t)8 * N_NODES * 2);
    float* Rc2  = (float*)alloc((size_t)N_NODES * 4);
    float* Tc2  = (float*)alloc((size_t)N_NODES * 4);
    ushort* G2b2 = (ushort*)alloc((size_t)N_NODES * 2);
    ushort* Wh1 = (ushort*)alloc((size_t)8 * 64 * 256 * 2);
    ushort* Wl1 = (ushort*)alloc((size_t)8 * 64 * 256 * 2);
    ushort* Wh2 = (ushort*)alloc((size_t)64 * 512 * 2);
    ushort* Wl2 = (ushort*)alloc((size_t)64 * 512 * 2);
    ushort* accP = (ushort*)alloc((size_t)slices * N_NODES * 64 * 2);
    float* Zp   = (float*)alloc((size_t)slices * N_NODES * 4);

    hipLaunchKernelGGL(k_prologue, dim3(2688), dim3(256), 0, stream,
                       adj, maskw, W_heads, Wh1, Wl1, W_out, Wh2, Wl2);
    // layer 1
    hipLaunchKernelGGL(k_gemm_h, dim3(N_NODES / 16, 8), dim3(512), 0, stream,
                       features, Wh1, Wl1, a_heads, Ht1, Rc1, Tc1, G2b1, 256);
    if (tier == 2)
        hipLaunchKernelGGL((k_attn<4, 8>), dim3(32 * 4 * 8), dim3(256), 0, stream,
                           Ht1, Rc1, Tc1, G2b1, maskw, accP, Zp);
    else if (tier == 1)
        hipLaunchKernelGGL((k_attn<2, 8>), dim3(32 * 2 * 8), dim3(256), 0, stream,
                           Ht1, Rc1, Tc1, G2b1, maskw, accP, Zp);
    else
        hipLaunchKernelGGL((k_attn<1, 8>), dim3(32 * 1 * 8), dim3(256), 0, stream,
                           Ht1, Rc1, Tc1, G2b1, maskw, accP, Zp);
    // layer 2 (combine1 fused into the GEMM)
    if (tier == 2)
        hipLaunchKernelGGL((k_gemm2<4>), dim3(N_NODES / 16), dim3(512), 0, stream,
                           accP, Zp, Wh2, Wl2, a_out, Ht2, Rc2, Tc2, G2b2);
    else if (tier == 1)
        hipLaunchKernelGGL((k_gemm2<2>), dim3(N_NODES / 16), dim3(512), 0, stream,
                           accP, Zp, Wh2, Wl2, a_out, Ht2, Rc2, Tc2, G2b2);
    else
        hipLaunchKernelGGL((k_gemm2<1>), dim3(N_NODES / 16), dim3(512), 0, stream,
                           accP, Zp, Wh2, Wl2, a_out, Ht2, Rc2, Tc2, G2b2);
    if (tier == 2) {
        hipLaunchKernelGGL((k_attn<32, 1>), dim3(32 * 32), dim3(256), 0, stream,
                           Ht2, Rc2, Tc2, G2b2, maskw, accP, Zp);
        hipLaunchKernelGGL((k_combine2<32>), dim3(N_NODES * 64 / 256), dim3(256), 0, stream,
                           accP, Zp, out);
    } else if (tier == 1) {
        hipLaunchKernelGGL((k_attn<16, 1>), dim3(32 * 16), dim3(256), 0, stream,
                           Ht2, Rc2, Tc2, G2b2, maskw, accP, Zp);
        hipLaunchKernelGGL((k_combine2<16>), dim3(N_NODES * 64 / 256), dim3(256), 0, stream,
                           accP, Zp, out);
    } else {
        hipLaunchKernelGGL((k_attn<8, 1>), dim3(32 * 8), dim3(256), 0, stream,
                           Ht2, Rc2, Tc2, G2b2, maskw, accP, Zp);
        hipLaunchKernelGGL((k_combine2<8>), dim3(N_NODES * 64 / 256), dim3(256), 0, stream,
                           accP, Zp, out);
    }
}